// Round 11
// baseline (7717.968 us; speedup 1.0000x reference)
//
#include <hip/hip_runtime.h>

typedef __bf16 bf16;
typedef __bf16 bf16x8 __attribute__((ext_vector_type(8)));
typedef __bf16 bf16x4 __attribute__((ext_vector_type(4)));
typedef float  f32x4  __attribute__((ext_vector_type(4)));

#define T_LEN 70
#define BATCH 64
#define HDIM  1024
#define GDIM  4096
#define VOCAB 32000
#define TBROW (T_LEN * BATCH)   // 4480

#define MFMA16(a, b, c) __builtin_amdgcn_mfma_f32_16x16x32_bf16((a), (b), (c), 0, 0, 0)

typedef const __attribute__((address_space(1))) void gas_void;
typedef __attribute__((address_space(3))) void las_void;

// ---------------------------------------------------------------------------
__global__ void split_kernel(const float* __restrict__ w, bf16* __restrict__ hi,
                             bf16* __restrict__ lo, int n4) {
    int stride = gridDim.x * blockDim.x;
    for (int i = blockIdx.x * blockDim.x + threadIdx.x; i < n4; i += stride) {
        float4 v = reinterpret_cast<const float4*>(w)[i];
        bf16 h0 = (bf16)v.x, h1 = (bf16)v.y, h2 = (bf16)v.z, h3 = (bf16)v.w;
        bf16x4 hv = {h0, h1, h2, h3};
        bf16x4 lv = {(bf16)(v.x - (float)h0), (bf16)(v.y - (float)h1),
                     (bf16)(v.z - (float)h2), (bf16)(v.w - (float)h3)};
        reinterpret_cast<bf16x4*>(hi)[i] = hv;
        reinterpret_cast<bf16x4*>(lo)[i] = lv;
    }
}

__global__ void conv_kernel(const float* __restrict__ w, bf16* __restrict__ hi, int n4) {
    int stride = gridDim.x * blockDim.x;
    for (int i = blockIdx.x * blockDim.x + threadIdx.x; i < n4; i += stride) {
        float4 v = reinterpret_cast<const float4*>(w)[i];
        bf16x4 hv = {(bf16)v.x, (bf16)v.y, (bf16)v.z, (bf16)v.w};
        reinterpret_cast<bf16x4*>(hi)[i] = hv;
    }
}

__global__ void embed_kernel(const int* __restrict__ x, const float* __restrict__ emb,
                             bf16* __restrict__ xh, bf16* __restrict__ xl) {
    int row = blockIdx.x;
    int tok = x[row];
    const float4* src = reinterpret_cast<const float4*>(emb + (size_t)tok * HDIM);
    bf16x4* dh = reinterpret_cast<bf16x4*>(xh + (size_t)row * HDIM);
    bf16x4* dl = reinterpret_cast<bf16x4*>(xl + (size_t)row * HDIM);
    for (int i = threadIdx.x; i < HDIM / 4; i += blockDim.x) {
        float4 v = src[i];
        bf16 h0 = (bf16)v.x, h1 = (bf16)v.y, h2 = (bf16)v.z, h3 = (bf16)v.w;
        dh[i] = (bf16x4){h0, h1, h2, h3};
        dl[i] = (bf16x4){(bf16)(v.x - (float)h0), (bf16)(v.y - (float)h1),
                         (bf16)(v.z - (float)h2), (bf16)(v.w - (float)h3)};
    }
}

// initial h stored at parity 1 (first reads occur at input-parity 1)
__global__ void init_kernel(const float* __restrict__ h0, const float* __restrict__ c0,
                            bf16* __restrict__ hsb, float* __restrict__ cst) {
    int i = blockIdx.x * blockDim.x + threadIdx.x;
    int l = i >> 16, r = i & 65535;
    float v = h0[i];
    bf16 h = (bf16)v;
    hsb[(size_t)((l * 2 + 1) * 2 + 0) * 65536 + r] = h;
    hsb[(size_t)((l * 2 + 1) * 2 + 1) * 65536 + r] = (bf16)(v - (float)h);
    cst[i] = c0[i];
}

// ---------------------------------------------------------------------------
// GEMM C = sum_p A_p B_p^T + bias (unchanged)
// ---------------------------------------------------------------------------
__global__ __launch_bounds__(256) void gemm_bt(
    const bf16* __restrict__ a0, const bf16* __restrict__ a1, const bf16* __restrict__ a2,
    const bf16* __restrict__ b0, const bf16* __restrict__ b1, const bf16* __restrict__ b2,
    int npass, int K, const float* __restrict__ bias, float* __restrict__ C, int ldc) {
    __shared__ __align__(16) char As[128 * 128];
    __shared__ __align__(16) char Bs[128 * 128];
    const int tid = threadIdx.x;
    const int wid = tid >> 6, lane = tid & 63;
    const int l15 = lane & 15, l4 = lane >> 4;

    const int nbx = gridDim.x, mt = gridDim.y, nwg = nbx * mt;
    const int flat = blockIdx.y * nbx + blockIdx.x;
    const int xcd = flat & 7, o8 = flat >> 3;
    const int q8 = nwg >> 3, r8 = nwg & 7;
    const int wg = (xcd < r8 ? xcd * (q8 + 1) : r8 * (q8 + 1) + (xcd - r8) * q8) + o8;
    const int m0 = (wg % mt) * 128, n0 = (wg / mt) * 128;

    const int wr = (wid >> 1) * 64, wc = (wid & 1) * 64;
    const int swz_rd = (l15 & 7) << 4;
    const int rowL = lane >> 3;
    const int colE = (((lane & 7) ^ rowL)) << 3;

    f32x4 acc[4][4];
#pragma unroll
    for (int i = 0; i < 4; ++i)
#pragma unroll
        for (int j = 0; j < 4; ++j) acc[i][j] = (f32x4){0.f, 0.f, 0.f, 0.f};

    for (int p = 0; p < npass; ++p) {
        const bf16* A = (p == 0) ? a0 : ((p == 1) ? a1 : a2);
        const bf16* B = (p == 0) ? b0 : ((p == 1) ? b1 : b2);
        for (int k0 = 0; k0 < K; k0 += 64) {
            __syncthreads();
#pragma unroll
            for (int c2 = 0; c2 < 4; ++c2) {
                const int ch = wid * 4 + c2;
                const int row = ch * 8 + rowL;
                __builtin_amdgcn_global_load_lds(
                    (gas_void*)(A + (size_t)(m0 + row) * K + k0 + colE),
                    (las_void*)(As + ch * 1024), 16, 0, 0);
                __builtin_amdgcn_global_load_lds(
                    (gas_void*)(B + (size_t)(n0 + row) * K + k0 + colE),
                    (las_void*)(Bs + ch * 1024), 16, 0, 0);
            }
            __syncthreads();
#pragma unroll
            for (int ks = 0; ks < 2; ++ks) {
                const int cb = (ks * 64 + l4 * 16) ^ swz_rd;
                bf16x8 af[4], bfr[4];
#pragma unroll
                for (int mi = 0; mi < 4; ++mi)
                    af[mi] = *reinterpret_cast<const bf16x8*>(As + (wr + mi * 16 + l15) * 128 + cb);
#pragma unroll
                for (int ni = 0; ni < 4; ++ni)
                    bfr[ni] = *reinterpret_cast<const bf16x8*>(Bs + (wc + ni * 16 + l15) * 128 + cb);
#pragma unroll
                for (int mi = 0; mi < 4; ++mi)
#pragma unroll
                    for (int ni = 0; ni < 4; ++ni)
                        acc[mi][ni] = MFMA16(af[mi], bfr[ni], acc[mi][ni]);
            }
        }
    }
#pragma unroll
    for (int ni = 0; ni < 4; ++ni) {
        const int col = n0 + wc + ni * 16 + l15;
        const float bv = bias[col];
#pragma unroll
        for (int mi = 0; mi < 4; ++mi) {
            const int row0 = m0 + wr + mi * 16 + l4 * 4;
#pragma unroll
            for (int r = 0; r < 4; ++r)
                C[(size_t)(row0 + r) * ldc + col] = acc[mi][ni][r] + bv;
        }
    }
}

// ---------------------------------------------------------------------------
// Persistent-weight wavefront LSTM v7 = v6 + CBAR race fix.
// Each block pins its 16 gate-cols of all 5 weight matrices (hi+lo, 320 KB)
// in VGPRs. Waves are K-slices; partial sums reduced via LDS atomics into 3
// rotating regions. A (h hi/lo) staged via global_load_lds, double-buffered.
// CBAR (lgkmcnt(0)+barrier) between COMPUTE(buf) and ISSUE(->same buf)
// guarantees no wave's pending LDS reads can see the next chunk's data.
// ---------------------------------------------------------------------------
__global__ __launch_bounds__(512, 1) void lstm_wave(
    const float* __restrict__ cin,
    const bf16* __restrict__ Wh0h, const bf16* __restrict__ Wh0l,
    const bf16* __restrict__ Wi1h, const bf16* __restrict__ Wi1l,
    const bf16* __restrict__ Wh1h, const bf16* __restrict__ Wh1l,
    const bf16* __restrict__ Wi2h, const bf16* __restrict__ Wi2l,
    const bf16* __restrict__ Wh2h, const bf16* __restrict__ Wh2l,
    const float* __restrict__ px0,
    const float* __restrict__ bh0, const float* __restrict__ bi1,
    const float* __restrict__ bh1, const float* __restrict__ bi2,
    const float* __restrict__ bh2,
    bf16* __restrict__ hsb, bf16* __restrict__ outh, int* __restrict__ bar,
    bf16* __restrict__ dump) {
    __shared__ __align__(16) char smem[143360];

    const int tid = threadIdx.x;
    const int lane = tid & 63, w = tid >> 6;
    const int l15 = lane & 15, l4 = lane >> 4;
    const int j0 = blockIdx.x * 4;
    const int lcol = (l15 >> 2) * 1024 + j0 + (l15 & 3);  // gate col for B-frag
    // gates
    const int gb = tid >> 2, gj = tid & 3;

    // ---- persistent weight fragments: wg[matrix][hi/lo][ks] ----
    // matrix: 0=Wh0 1=Wi1 2=Wh1 3=Wi2 4=Wh2
    bf16x8 wg[5][2][4];
    {
        const bf16* wp[5][2] = {{Wh0h, Wh0l}, {Wi1h, Wi1l}, {Wh1h, Wh1l},
                                {Wi2h, Wi2l}, {Wh2h, Wh2l}};
#pragma unroll
        for (int m = 0; m < 5; ++m)
#pragma unroll
            for (int hl = 0; hl < 2; ++hl)
#pragma unroll
                for (int ks = 0; ks < 4; ++ks)
                    wg[m][hl][ks] = *reinterpret_cast<const bf16x8*>(
                        wp[m][hl] + (size_t)lcol * HDIM + w * 128 + ks * 32 + l4 * 8);
    }

    float creg0 = 0.f, creg1 = 0.f, creg2 = 0.f;
    if (tid < 256) {
        creg0 = cin[0 * 65536 + gb * 1024 + j0 + gj];
        creg1 = cin[1 * 65536 + gb * 1024 + j0 + gj];
        creg2 = cin[2 * 65536 + gb * 1024 + j0 + gj];
    }
    // zero the 3 reduction regions
    for (int i = tid; i < 3072; i += 512)
        reinterpret_cast<float*>(smem + 131072)[i] = 0.f;
    asm volatile("s_waitcnt vmcnt(0) lgkmcnt(0)" ::: "memory");
    __syncthreads();

    auto hsp = [&](int l, int par, int hl) {
        return hsb + (((size_t)l * 2 + par) * 2 + hl) * 65536;
    };

    bf16* const nullp = nullptr;
    int barid = 0;

    f32x4 a0[4], a1[4];
#pragma unroll
    for (int c = 0; c < 4; ++c) {
        a0[c] = (f32x4){0.f, 0.f, 0.f, 0.f};
        a1[c] = (f32x4){0.f, 0.f, 0.f, 0.f};
    }

#define WBAR(N)                                                                   \
    {                                                                             \
        asm volatile("s_waitcnt vmcnt(" #N ")" ::: "memory");                     \
        __builtin_amdgcn_s_barrier();                                             \
        __builtin_amdgcn_sched_barrier(0);                                        \
    }

// compute-done barrier: all waves' LDS reads COMPLETE before anyone overwrites
#define CBAR()                                                                    \
    {                                                                             \
        asm volatile("s_waitcnt lgkmcnt(0)" ::: "memory");                        \
        __builtin_amdgcn_s_barrier();                                             \
        __builtin_amdgcn_sched_barrier(0);                                        \
    }

// stage one 16-row A chunk (hi+lo, 64KB) into buf; 8 gload_lds per wave.
// waves 0-3 stage hi, 4-7 stage lo; pre-swizzled source, linear LDS dest.
#define ISSUE(AH, AL, CROW, buf)                                                  \
    {                                                                             \
        const bf16* pa_ = (w >> 2) ? (AL) : (AH);                                 \
        _Pragma("unroll") for (int i_ = 0; i_ < 8; ++i_) {                        \
            const int r2_ = (w & 3) * 8 + i_;                                     \
            const int row_ = r2_ >> 1, kh_ = r2_ & 1;                             \
            const int sb_ = (kh_ * 1024 + lane * 16) ^ (row_ << 4);               \
            __builtin_amdgcn_global_load_lds(                                     \
                (gas_void*)(pa_ + (size_t)((CROW) + row_) * HDIM + (sb_ >> 1)),   \
                (las_void*)(smem + (buf) * 65536 + (w >> 2) * 32768 +             \
                            row_ * 2048 + kh_ * 1024), 16, 0, 0);                 \
        }                                                                         \
    }

// one chunk's MFMA work: wave's 128-k slice, 4 k-steps, 3-pass split.
#define COMPUTE(buf, U0, U1, HASU1, OK0, OK1, C)                                  \
    {                                                                             \
        const char* base_ = smem + (buf) * 65536;                                 \
        _Pragma("unroll") for (int ks_ = 0; ks_ < 4; ++ks_) {                     \
            const int kb_ = (w * 256 + ks_ * 64 + l4 * 16) ^ (l15 << 4);          \
            bf16x8 ah_ = *reinterpret_cast<const bf16x8*>(base_ + l15 * 2048 + kb_);          \
            bf16x8 al_ = *reinterpret_cast<const bf16x8*>(base_ + 32768 + l15 * 2048 + kb_);  \
            if (OK0) {                                                            \
                a0[C] = MFMA16(ah_, wg[U0][0][ks_], a0[C]);                       \
                a0[C] = MFMA16(ah_, wg[U0][1][ks_], a0[C]);                       \
                a0[C] = MFMA16(al_, wg[U0][0][ks_], a0[C]);                       \
            }                                                                     \
            if (HASU1) {                                                          \
                if (OK1) {                                                        \
                    a1[C] = MFMA16(ah_, wg[U1][0][ks_], a1[C]);                   \
                    a1[C] = MFMA16(ah_, wg[U1][1][ks_], a1[C]);                   \
                    a1[C] = MFMA16(al_, wg[U1][0][ks_], a1[C]);                   \
                }                                                                 \
            }                                                                     \
        }                                                                         \
    }

#define ATOMADD(RO, A)                                                            \
    {                                                                             \
        float* R_ = reinterpret_cast<float*>(smem + 131072 + (RO) * 4096);        \
        _Pragma("unroll") for (int c_ = 0; c_ < 4; ++c_)                          \
            _Pragma("unroll") for (int r_ = 0; r_ < 4; ++r_)                      \
                atomicAdd(&R_[(c_ * 16 + l4 * 4 + r_) * 16 + l15], (A)[c_][r_]);  \
    }

#define ZEROACC                                                                   \
    {                                                                             \
        _Pragma("unroll") for (int c_ = 0; c_ < 4; ++c_) {                        \
            a0[c_] = (f32x4){0.f, 0.f, 0.f, 0.f};                                 \
            a1[c_] = (f32x4){0.f, 0.f, 0.f, 0.f};                                 \
        }                                                                         \
    }

// gate phase: consume region(s), update c/h, zero regions; ends fully drained.
#define GATE(RA, RB, HASB, USEPX, SREAD, ACT, HH, HL, OHP, CREG, BI, HASBI, BH)   \
    {                                                                             \
        asm volatile("s_waitcnt lgkmcnt(0)" ::: "memory");                        \
        __builtin_amdgcn_s_barrier();                                             \
        __builtin_amdgcn_sched_barrier(0);                                        \
        if (tid < 256) {                                                          \
            float* Ra_ = reinterpret_cast<float*>(smem + 131072 + (RA) * 4096);   \
            float* Rb_ = reinterpret_cast<float*>(smem + 131072 + (RB) * 4096);   \
            float p_[4];                                                          \
            _Pragma("unroll") for (int q_ = 0; q_ < 4; ++q_) {                    \
                p_[q_] = Ra_[gb * 16 + q_ * 4 + gj];                              \
                if (HASB) p_[q_] += Rb_[gb * 16 + q_ * 4 + gj];                   \
                p_[q_] += (BH)[q_ * 1024 + j0 + gj];                              \
                if (HASBI) p_[q_] += (BI)[q_ * 1024 + j0 + gj];                   \
                if (USEPX) p_[q_] += px0[(size_t)(SREAD) * (BATCH * GDIM) +       \
                                         (size_t)gb * GDIM + q_ * 1024 + j0 + gj]; \
            }                                                                     \
            const float ig = 1.f / (1.f + expf(-p_[0]));                          \
            const float fg = 1.f / (1.f + expf(-p_[1]));                          \
            const float og = 1.f / (1.f + expf(-p_[2]));                          \
            const float gg = tanhf(p_[3]);                                        \
            const float c2v = fg * (CREG) + ig * gg;                              \
            const float h2v = og * tanhf(c2v);                                    \
            if (ACT) (CREG) = c2v;                                                \
            const int idx = gb * 1024 + j0 + gj;                                  \
            const bf16 hhi = (bf16)h2v;                                           \
            (HH)[idx] = hhi;                                                      \
            (HL)[idx] = (bf16)(h2v - (float)hhi);                                 \
            if ((OHP) != nullptr) (OHP)[idx] = hhi;                               \
            _Pragma("unroll") for (int q_ = 0; q_ < 4; ++q_) {                    \
                Ra_[gb * 16 + q_ * 4 + gj] = 0.f;                                 \
                if (HASB) Rb_[gb * 16 + q_ * 4 + gj] = 0.f;                       \
            }                                                                     \
        }                                                                         \
        asm volatile("s_waitcnt vmcnt(0) lgkmcnt(0)" ::: "memory");               \
        __builtin_amdgcn_s_barrier();                                             \
        __builtin_amdgcn_sched_barrier(0);                                        \
    }

#pragma unroll 1
    for (int s = 0; s < T_LEN + 2; ++s) {
        const int ps = s & 1;
        const bool act0 = (s < T_LEN);
        const bool act1 = (s >= 1) && (s <= T_LEN);
        const bool act2 = (s >= 2);
        const int sread = act0 ? s : 0;

        const bf16* A0h = hsp(0, 1 - ps, 0); const bf16* A0l = hsp(0, 1 - ps, 1);
        const bf16* A1h = hsp(1, ps, 0);     const bf16* A1l = hsp(1, ps, 1);
        const bf16* A2h = hsp(2, 1 - ps, 0); const bf16* A2l = hsp(2, 1 - ps, 1);
        bf16* dH0h = act0 ? hsp(0, ps, 0)     : dump;
        bf16* dH0l = act0 ? hsp(0, ps, 1)     : dump;
        bf16* dH1h = act1 ? hsp(1, 1 - ps, 0) : dump;
        bf16* dH1l = act1 ? hsp(1, 1 - ps, 1) : dump;
        bf16* dH2h = act2 ? hsp(2, ps, 0)     : dump;
        bf16* dH2l = act2 ? hsp(2, ps, 1)     : dump;
        bf16* ohp  = act2 ? (outh + (size_t)(s - 2) * 65536) : dump;

        // ---- group 0: A0 x {Wh0 -> R0 (cell0), Wi1 -> R1 (cell1 partial)} ----
        ISSUE(A0h, A0l, 0, 0)
        ISSUE(A0h, A0l, 16, 1)
        WBAR(8) COMPUTE(0, 0, 1, 1, act0, act1, 0) CBAR() ISSUE(A0h, A0l, 32, 0)
        WBAR(8) COMPUTE(1, 0, 1, 1, act0, act1, 1) CBAR() ISSUE(A0h, A0l, 48, 1)
        WBAR(8) COMPUTE(0, 0, 1, 1, act0, act1, 2) CBAR() ISSUE(A1h, A1l, 0, 0)
        WBAR(8) COMPUTE(1, 0, 1, 1, act0, act1, 3)
        ATOMADD(0, a0) ATOMADD(1, a1)
        GATE(0, 0, 0, 1, sread, act0, dH0h, dH0l, nullp, creg0, bh0, 0, bh0)
        ZEROACC
        ISSUE(A1h, A1l, 16, 1)

        // ---- group 1: A1 x {Wh1 -> R0 (cell1), Wi2 -> R2 (cell2 partial)} ----
        WBAR(8) COMPUTE(0, 2, 3, 1, act1, act2, 0) CBAR() ISSUE(A1h, A1l, 32, 0)
        WBAR(8) COMPUTE(1, 2, 3, 1, act1, act2, 1) CBAR() ISSUE(A1h, A1l, 48, 1)
        WBAR(8) COMPUTE(0, 2, 3, 1, act1, act2, 2) CBAR() ISSUE(A2h, A2l, 0, 0)
        WBAR(8) COMPUTE(1, 2, 3, 1, act1, act2, 3)
        ATOMADD(0, a0) ATOMADD(2, a1)
        GATE(1, 0, 1, 0, 0, act1, dH1h, dH1l, nullp, creg1, bi1, 1, bh1)
        ZEROACC
        ISSUE(A2h, A2l, 16, 1)

        // ---- group 2: A2 x {Wh2 -> R0 (cell2)} ----
        WBAR(8) COMPUTE(0, 4, 4, 0, act2, act2, 0) CBAR() ISSUE(A2h, A2l, 32, 0)
        WBAR(8) COMPUTE(1, 4, 4, 0, act2, act2, 1) CBAR() ISSUE(A2h, A2l, 48, 1)
        WBAR(8) COMPUTE(0, 4, 4, 0, act2, act2, 2)
        WBAR(0) COMPUTE(1, 4, 4, 0, act2, act2, 3)
        ATOMADD(0, a0)
        GATE(0, 2, 1, 0, 0, act2, dH2h, dH2l, ohp, creg2, bi2, 1, bh2)
        ZEROACC

        // ---- grid barrier ----
        if (s < T_LEN + 1) {
            if (tid == 0) {
                int* slot = bar + barid * 128 + (blockIdx.x & 7) * 16;
                __hip_atomic_fetch_add(slot, 1, __ATOMIC_RELEASE,
                                       __HIP_MEMORY_SCOPE_AGENT);
                for (;;) {
                    int sum = 0;
#pragma unroll
                    for (int k = 0; k < 8; ++k)
                        sum += __hip_atomic_load(bar + barid * 128 + k * 16,
                                                 __ATOMIC_RELAXED,
                                                 __HIP_MEMORY_SCOPE_AGENT);
                    if (sum >= (int)gridDim.x) break;
                    __builtin_amdgcn_s_sleep(2);
                }
                __builtin_amdgcn_fence(__ATOMIC_ACQUIRE, "agent");
            }
            ++barid;
            __builtin_amdgcn_s_barrier();
            __builtin_amdgcn_sched_barrier(0);
        }
    }
#undef WBAR
#undef CBAR
#undef ISSUE
#undef COMPUTE
#undef ATOMADD
#undef ZEROACC
#undef GATE
}

// ---------------------------------------------------------------------------
extern "C" void kernel_launch(void* const* d_in, const int* in_sizes, int n_in,
                              void* d_out, int out_size, void* d_ws, size_t ws_size,
                              hipStream_t stream) {
    (void)in_sizes; (void)n_in; (void)out_size; (void)ws_size;
    const int*   x   = (const int*)d_in[0];
    const float* h0  = (const float*)d_in[1];
    const float* c0  = (const float*)d_in[2];
    const float* emb = (const float*)d_in[3];
    const float* W[6] = { (const float*)d_in[4],  (const float*)d_in[6],
                          (const float*)d_in[8],  (const float*)d_in[10],
                          (const float*)d_in[12], (const float*)d_in[14] };
    const float* bi0 = (const float*)d_in[5];
    const float* bh0 = (const float*)d_in[7];
    const float* bi1 = (const float*)d_in[9];
    const float* bh1 = (const float*)d_in[11];
    const float* bi2 = (const float*)d_in[13];
    const float* bh2 = (const float*)d_in[15];
    const float* Wd  = (const float*)d_in[16];
    const float* bd  = (const float*)d_in[17];

    char* ws = (char*)d_ws;
    size_t off = 0;
    float* px0 = (float*)(ws + off); off += (size_t)TBROW * GDIM * 4;
    bf16* wsp[12];
    for (int i = 0; i < 12; ++i) { wsp[i] = (bf16*)(ws + off); off += (size_t)GDIM * HDIM * 2; }
    bf16* wdb  = (bf16*)(ws + off); off += (size_t)VOCAB * HDIM * 2;
    bf16* xeh  = (bf16*)(ws + off); off += (size_t)TBROW * HDIM * 2;
    bf16* xel  = (bf16*)(ws + off); off += (size_t)TBROW * HDIM * 2;
    bf16* outh = (bf16*)(ws + off); off += (size_t)TBROW * HDIM * 2;
    bf16* hsb  = (bf16*)(ws + off); off += (size_t)12 * BATCH * HDIM * 2;
    float* cst = (float*)(ws + off); off += (size_t)3 * BATCH * HDIM * 4;
    int*  bar  = (int*)(ws + off);  off += 72 * 128 * 4;
    bf16* dump = (bf16*)(ws + off); off += (size_t)BATCH * HDIM * 2;

    // wsp[0..1]=Wi0, [2..3]=Wh0, [4..5]=Wi1, [6..7]=Wh1, [8..9]=Wi2, [10..11]=Wh2
    for (int i = 0; i < 6; ++i)
        split_kernel<<<1024, 256, 0, stream>>>(W[i], wsp[2 * i], wsp[2 * i + 1],
                                               GDIM * HDIM / 4);
    conv_kernel<<<2048, 256, 0, stream>>>(Wd, wdb, VOCAB * HDIM / 4);
    embed_kernel<<<TBROW, 256, 0, stream>>>(x, emb, xeh, xel);
    init_kernel<<<768, 256, 0, stream>>>(h0, c0, hsb, cst);
    (void)hipMemsetAsync(bar, 0, 72 * 128 * 4, stream);

    // px0 = xe @ Wi0^T + bi0 (split-3)
    dim3 gpx(GDIM / 128, TBROW / 128);
    gemm_bt<<<gpx, 256, 0, stream>>>(xeh, xel, xeh, wsp[0], wsp[0], wsp[1],
                                     3, HDIM, bi0, px0, GDIM);

    // whole recurrence: persistent weights in VGPRs
    lstm_wave<<<256, 512, 0, stream>>>(
        c0,
        wsp[2], wsp[3],           // Wh0
        wsp[4], wsp[5],           // Wi1
        wsp[6], wsp[7],           // Wh1
        wsp[8], wsp[9],           // Wi2
        wsp[10], wsp[11],         // Wh2
        px0, bh0, bi1, bh1, bi2, bh2,
        hsb, outh, bar, dump);

    // decoder: d_out = outh @ Wd^T + bd
    dim3 gdec(VOCAB / 128, TBROW / 128);
    gemm_bt<<<gdec, 256, 0, stream>>>(outh, nullptr, nullptr, wdb, nullptr, nullptr,
                                      1, HDIM, bd, (float*)d_out, VOCAB);
}

// Round 12
// 7699.294 us; speedup vs baseline: 1.0024x; 1.0024x over previous
//
#include <hip/hip_runtime.h>

typedef __bf16 bf16;
typedef __bf16 bf16x8 __attribute__((ext_vector_type(8)));
typedef __bf16 bf16x4 __attribute__((ext_vector_type(4)));
typedef float  f32x4  __attribute__((ext_vector_type(4)));

#define T_LEN 70
#define BATCH 64
#define HDIM  1024
#define GDIM  4096
#define VOCAB 32000
#define TBROW (T_LEN * BATCH)   // 4480

#define MFMA16(a, b, c) __builtin_amdgcn_mfma_f32_16x16x32_bf16((a), (b), (c), 0, 0, 0)

typedef const __attribute__((address_space(1))) void gas_void;
typedef __attribute__((address_space(3))) void las_void;

// ---------------------------------------------------------------------------
__global__ void split_kernel(const float* __restrict__ w, bf16* __restrict__ hi,
                             bf16* __restrict__ lo, int n4) {
    int stride = gridDim.x * blockDim.x;
    for (int i = blockIdx.x * blockDim.x + threadIdx.x; i < n4; i += stride) {
        float4 v = reinterpret_cast<const float4*>(w)[i];
        bf16 h0 = (bf16)v.x, h1 = (bf16)v.y, h2 = (bf16)v.z, h3 = (bf16)v.w;
        bf16x4 hv = {h0, h1, h2, h3};
        bf16x4 lv = {(bf16)(v.x - (float)h0), (bf16)(v.y - (float)h1),
                     (bf16)(v.z - (float)h2), (bf16)(v.w - (float)h3)};
        reinterpret_cast<bf16x4*>(hi)[i] = hv;
        reinterpret_cast<bf16x4*>(lo)[i] = lv;
    }
}

__global__ void conv_kernel(const float* __restrict__ w, bf16* __restrict__ hi, int n4) {
    int stride = gridDim.x * blockDim.x;
    for (int i = blockIdx.x * blockDim.x + threadIdx.x; i < n4; i += stride) {
        float4 v = reinterpret_cast<const float4*>(w)[i];
        bf16x4 hv = {(bf16)v.x, (bf16)v.y, (bf16)v.z, (bf16)v.w};
        reinterpret_cast<bf16x4*>(hi)[i] = hv;
    }
}

__global__ void embed_kernel(const int* __restrict__ x, const float* __restrict__ emb,
                             bf16* __restrict__ xh, bf16* __restrict__ xl) {
    int row = blockIdx.x;
    int tok = x[row];
    const float4* src = reinterpret_cast<const float4*>(emb + (size_t)tok * HDIM);
    bf16x4* dh = reinterpret_cast<bf16x4*>(xh + (size_t)row * HDIM);
    bf16x4* dl = reinterpret_cast<bf16x4*>(xl + (size_t)row * HDIM);
    for (int i = threadIdx.x; i < HDIM / 4; i += blockDim.x) {
        float4 v = src[i];
        bf16 h0 = (bf16)v.x, h1 = (bf16)v.y, h2 = (bf16)v.z, h3 = (bf16)v.w;
        dh[i] = (bf16x4){h0, h1, h2, h3};
        dl[i] = (bf16x4){(bf16)(v.x - (float)h0), (bf16)(v.y - (float)h1),
                         (bf16)(v.z - (float)h2), (bf16)(v.w - (float)h3)};
    }
}

// initial h stored at parity 1 (first reads occur at input-parity 1)
__global__ void init_kernel(const float* __restrict__ h0, const float* __restrict__ c0,
                            bf16* __restrict__ hsb, float* __restrict__ cst) {
    int i = blockIdx.x * blockDim.x + threadIdx.x;
    int l = i >> 16, r = i & 65535;
    float v = h0[i];
    bf16 h = (bf16)v;
    hsb[(size_t)((l * 2 + 1) * 2 + 0) * 65536 + r] = h;
    hsb[(size_t)((l * 2 + 1) * 2 + 1) * 65536 + r] = (bf16)(v - (float)h);
    cst[i] = c0[i];
}

// ---------------------------------------------------------------------------
// GEMM C = sum_p A_p B_p^T + bias (unchanged)
// ---------------------------------------------------------------------------
__global__ __launch_bounds__(256) void gemm_bt(
    const bf16* __restrict__ a0, const bf16* __restrict__ a1, const bf16* __restrict__ a2,
    const bf16* __restrict__ b0, const bf16* __restrict__ b1, const bf16* __restrict__ b2,
    int npass, int K, const float* __restrict__ bias, float* __restrict__ C, int ldc) {
    __shared__ __align__(16) char As[128 * 128];
    __shared__ __align__(16) char Bs[128 * 128];
    const int tid = threadIdx.x;
    const int wid = tid >> 6, lane = tid & 63;
    const int l15 = lane & 15, l4 = lane >> 4;

    const int nbx = gridDim.x, mt = gridDim.y, nwg = nbx * mt;
    const int flat = blockIdx.y * nbx + blockIdx.x;
    const int xcd = flat & 7, o8 = flat >> 3;
    const int q8 = nwg >> 3, r8 = nwg & 7;
    const int wg = (xcd < r8 ? xcd * (q8 + 1) : r8 * (q8 + 1) + (xcd - r8) * q8) + o8;
    const int m0 = (wg % mt) * 128, n0 = (wg / mt) * 128;

    const int wr = (wid >> 1) * 64, wc = (wid & 1) * 64;
    const int swz_rd = (l15 & 7) << 4;
    const int rowL = lane >> 3;
    const int colE = (((lane & 7) ^ rowL)) << 3;

    f32x4 acc[4][4];
#pragma unroll
    for (int i = 0; i < 4; ++i)
#pragma unroll
        for (int j = 0; j < 4; ++j) acc[i][j] = (f32x4){0.f, 0.f, 0.f, 0.f};

    for (int p = 0; p < npass; ++p) {
        const bf16* A = (p == 0) ? a0 : ((p == 1) ? a1 : a2);
        const bf16* B = (p == 0) ? b0 : ((p == 1) ? b1 : b2);
        for (int k0 = 0; k0 < K; k0 += 64) {
            __syncthreads();
#pragma unroll
            for (int c2 = 0; c2 < 4; ++c2) {
                const int ch = wid * 4 + c2;
                const int row = ch * 8 + rowL;
                __builtin_amdgcn_global_load_lds(
                    (gas_void*)(A + (size_t)(m0 + row) * K + k0 + colE),
                    (las_void*)(As + ch * 1024), 16, 0, 0);
                __builtin_amdgcn_global_load_lds(
                    (gas_void*)(B + (size_t)(n0 + row) * K + k0 + colE),
                    (las_void*)(Bs + ch * 1024), 16, 0, 0);
            }
            __syncthreads();
#pragma unroll
            for (int ks = 0; ks < 2; ++ks) {
                const int cb = (ks * 64 + l4 * 16) ^ swz_rd;
                bf16x8 af[4], bfr[4];
#pragma unroll
                for (int mi = 0; mi < 4; ++mi)
                    af[mi] = *reinterpret_cast<const bf16x8*>(As + (wr + mi * 16 + l15) * 128 + cb);
#pragma unroll
                for (int ni = 0; ni < 4; ++ni)
                    bfr[ni] = *reinterpret_cast<const bf16x8*>(Bs + (wc + ni * 16 + l15) * 128 + cb);
#pragma unroll
                for (int mi = 0; mi < 4; ++mi)
#pragma unroll
                    for (int ni = 0; ni < 4; ++ni)
                        acc[mi][ni] = MFMA16(af[mi], bfr[ni], acc[mi][ni]);
            }
        }
    }
#pragma unroll
    for (int ni = 0; ni < 4; ++ni) {
        const int col = n0 + wc + ni * 16 + l15;
        const float bv = bias[col];
#pragma unroll
        for (int mi = 0; mi < 4; ++mi) {
            const int row0 = m0 + wr + mi * 16 + l4 * 4;
#pragma unroll
            for (int r = 0; r < 4; ++r)
                C[(size_t)(row0 + r) * ldc + col] = acc[mi][ni][r] + bv;
        }
    }
}

// ---------------------------------------------------------------------------
// Persistent-weight wavefront LSTM v8 = v7 + forced 256-VGPR budget
// (amdgpu_waves_per_eu(2,2); LDS already limits to 1 block/CU = 2 waves/EU,
// so the wider register budget costs no occupancy). Weight file (160 VGPRs)
// must stay resident — r11's 128-reg budget spilled it to scratch.
// ---------------------------------------------------------------------------
__global__ __attribute__((amdgpu_flat_work_group_size(512, 512),
                          amdgpu_waves_per_eu(2, 2))) void lstm_wave(
    const float* __restrict__ cin,
    const bf16* __restrict__ Wh0h, const bf16* __restrict__ Wh0l,
    const bf16* __restrict__ Wi1h, const bf16* __restrict__ Wi1l,
    const bf16* __restrict__ Wh1h, const bf16* __restrict__ Wh1l,
    const bf16* __restrict__ Wi2h, const bf16* __restrict__ Wi2l,
    const bf16* __restrict__ Wh2h, const bf16* __restrict__ Wh2l,
    const float* __restrict__ px0,
    const float* __restrict__ bh0, const float* __restrict__ bi1,
    const float* __restrict__ bh1, const float* __restrict__ bi2,
    const float* __restrict__ bh2,
    bf16* __restrict__ hsb, bf16* __restrict__ outh, int* __restrict__ bar,
    bf16* __restrict__ dump) {
    __shared__ __align__(16) char smem[143360];

    const int tid = threadIdx.x;
    const int lane = tid & 63, w = tid >> 6;
    const int l15 = lane & 15, l4 = lane >> 4;
    const int j0 = blockIdx.x * 4;
    const int lcol = (l15 >> 2) * 1024 + j0 + (l15 & 3);  // gate col for B-frag
    // gates
    const int gb = tid >> 2, gj = tid & 3;

    // ---- persistent weight fragments: wg[matrix][hi/lo][ks] ----
    // matrix: 0=Wh0 1=Wi1 2=Wh1 3=Wi2 4=Wh2
    bf16x8 wg[5][2][4];
    {
        const bf16* wp[5][2] = {{Wh0h, Wh0l}, {Wi1h, Wi1l}, {Wh1h, Wh1l},
                                {Wi2h, Wi2l}, {Wh2h, Wh2l}};
#pragma unroll
        for (int m = 0; m < 5; ++m)
#pragma unroll
            for (int hl = 0; hl < 2; ++hl)
#pragma unroll
                for (int ks = 0; ks < 4; ++ks)
                    wg[m][hl][ks] = *reinterpret_cast<const bf16x8*>(
                        wp[m][hl] + (size_t)lcol * HDIM + w * 128 + ks * 32 + l4 * 8);
    }

    float creg0 = 0.f, creg1 = 0.f, creg2 = 0.f;
    if (tid < 256) {
        creg0 = cin[0 * 65536 + gb * 1024 + j0 + gj];
        creg1 = cin[1 * 65536 + gb * 1024 + j0 + gj];
        creg2 = cin[2 * 65536 + gb * 1024 + j0 + gj];
    }
    // zero the 3 reduction regions
    for (int i = tid; i < 3072; i += 512)
        reinterpret_cast<float*>(smem + 131072)[i] = 0.f;
    asm volatile("s_waitcnt vmcnt(0) lgkmcnt(0)" ::: "memory");
    __syncthreads();

    auto hsp = [&](int l, int par, int hl) {
        return hsb + (((size_t)l * 2 + par) * 2 + hl) * 65536;
    };

    bf16* const nullp = nullptr;
    int barid = 0;

    f32x4 a0[4], a1[4];
#pragma unroll
    for (int c = 0; c < 4; ++c) {
        a0[c] = (f32x4){0.f, 0.f, 0.f, 0.f};
        a1[c] = (f32x4){0.f, 0.f, 0.f, 0.f};
    }

#define WBAR(N)                                                                   \
    {                                                                             \
        asm volatile("s_waitcnt vmcnt(" #N ")" ::: "memory");                     \
        __builtin_amdgcn_s_barrier();                                             \
        __builtin_amdgcn_sched_barrier(0);                                        \
    }

// compute-done barrier: all waves' LDS reads COMPLETE before anyone overwrites
#define CBAR()                                                                    \
    {                                                                             \
        asm volatile("s_waitcnt lgkmcnt(0)" ::: "memory");                        \
        __builtin_amdgcn_s_barrier();                                             \
        __builtin_amdgcn_sched_barrier(0);                                        \
    }

// stage one 16-row A chunk (hi+lo, 64KB) into buf; 8 gload_lds per wave.
// waves 0-3 stage hi, 4-7 stage lo; pre-swizzled source, linear LDS dest.
#define ISSUE(AH, AL, CROW, buf)                                                  \
    {                                                                             \
        const bf16* pa_ = (w >> 2) ? (AL) : (AH);                                 \
        _Pragma("unroll") for (int i_ = 0; i_ < 8; ++i_) {                        \
            const int r2_ = (w & 3) * 8 + i_;                                     \
            const int row_ = r2_ >> 1, kh_ = r2_ & 1;                             \
            const int sb_ = (kh_ * 1024 + lane * 16) ^ (row_ << 4);               \
            __builtin_amdgcn_global_load_lds(                                     \
                (gas_void*)(pa_ + (size_t)((CROW) + row_) * HDIM + (sb_ >> 1)),   \
                (las_void*)(smem + (buf) * 65536 + (w >> 2) * 32768 +             \
                            row_ * 2048 + kh_ * 1024), 16, 0, 0);                 \
        }                                                                         \
    }

// one chunk's MFMA work: wave's 128-k slice, 4 k-steps, 3-pass split.
#define COMPUTE(buf, U0, U1, HASU1, OK0, OK1, C)                                  \
    {                                                                             \
        const char* base_ = smem + (buf) * 65536;                                 \
        _Pragma("unroll") for (int ks_ = 0; ks_ < 4; ++ks_) {                     \
            const int kb_ = (w * 256 + ks_ * 64 + l4 * 16) ^ (l15 << 4);          \
            bf16x8 ah_ = *reinterpret_cast<const bf16x8*>(base_ + l15 * 2048 + kb_);          \
            bf16x8 al_ = *reinterpret_cast<const bf16x8*>(base_ + 32768 + l15 * 2048 + kb_);  \
            if (OK0) {                                                            \
                a0[C] = MFMA16(ah_, wg[U0][0][ks_], a0[C]);                       \
                a0[C] = MFMA16(ah_, wg[U0][1][ks_], a0[C]);                       \
                a0[C] = MFMA16(al_, wg[U0][0][ks_], a0[C]);                       \
            }                                                                     \
            if (HASU1) {                                                          \
                if (OK1) {                                                        \
                    a1[C] = MFMA16(ah_, wg[U1][0][ks_], a1[C]);                   \
                    a1[C] = MFMA16(ah_, wg[U1][1][ks_], a1[C]);                   \
                    a1[C] = MFMA16(al_, wg[U1][0][ks_], a1[C]);                   \
                }                                                                 \
            }                                                                     \
        }                                                                         \
    }

#define ATOMADD(RO, A)                                                            \
    {                                                                             \
        float* R_ = reinterpret_cast<float*>(smem + 131072 + (RO) * 4096);        \
        _Pragma("unroll") for (int c_ = 0; c_ < 4; ++c_)                          \
            _Pragma("unroll") for (int r_ = 0; r_ < 4; ++r_)                      \
                atomicAdd(&R_[(c_ * 16 + l4 * 4 + r_) * 16 + l15], (A)[c_][r_]);  \
    }

#define ZEROACC                                                                   \
    {                                                                             \
        _Pragma("unroll") for (int c_ = 0; c_ < 4; ++c_) {                        \
            a0[c_] = (f32x4){0.f, 0.f, 0.f, 0.f};                                 \
            a1[c_] = (f32x4){0.f, 0.f, 0.f, 0.f};                                 \
        }                                                                         \
    }

// gate phase: consume region(s), update c/h, zero regions; ends fully drained.
#define GATE(RA, RB, HASB, USEPX, SREAD, ACT, HH, HL, OHP, CREG, BI, HASBI, BH)   \
    {                                                                             \
        asm volatile("s_waitcnt lgkmcnt(0)" ::: "memory");                        \
        __builtin_amdgcn_s_barrier();                                             \
        __builtin_amdgcn_sched_barrier(0);                                        \
        if (tid < 256) {                                                          \
            float* Ra_ = reinterpret_cast<float*>(smem + 131072 + (RA) * 4096);   \
            float* Rb_ = reinterpret_cast<float*>(smem + 131072 + (RB) * 4096);   \
            float p_[4];                                                          \
            _Pragma("unroll") for (int q_ = 0; q_ < 4; ++q_) {                    \
                p_[q_] = Ra_[gb * 16 + q_ * 4 + gj];                              \
                if (HASB) p_[q_] += Rb_[gb * 16 + q_ * 4 + gj];                   \
                p_[q_] += (BH)[q_ * 1024 + j0 + gj];                              \
                if (HASBI) p_[q_] += (BI)[q_ * 1024 + j0 + gj];                   \
                if (USEPX) p_[q_] += px0[(size_t)(SREAD) * (BATCH * GDIM) +       \
                                         (size_t)gb * GDIM + q_ * 1024 + j0 + gj]; \
            }                                                                     \
            const float ig = 1.f / (1.f + expf(-p_[0]));                          \
            const float fg = 1.f / (1.f + expf(-p_[1]));                          \
            const float og = 1.f / (1.f + expf(-p_[2]));                          \
            const float gg = tanhf(p_[3]);                                        \
            const float c2v = fg * (CREG) + ig * gg;                              \
            const float h2v = og * tanhf(c2v);                                    \
            if (ACT) (CREG) = c2v;                                                \
            const int idx = gb * 1024 + j0 + gj;                                  \
            const bf16 hhi = (bf16)h2v;                                           \
            (HH)[idx] = hhi;                                                      \
            (HL)[idx] = (bf16)(h2v - (float)hhi);                                 \
            if ((OHP) != nullptr) (OHP)[idx] = hhi;                               \
            _Pragma("unroll") for (int q_ = 0; q_ < 4; ++q_) {                    \
                Ra_[gb * 16 + q_ * 4 + gj] = 0.f;                                 \
                if (HASB) Rb_[gb * 16 + q_ * 4 + gj] = 0.f;                       \
            }                                                                     \
        }                                                                         \
        asm volatile("s_waitcnt vmcnt(0) lgkmcnt(0)" ::: "memory");               \
        __builtin_amdgcn_s_barrier();                                             \
        __builtin_amdgcn_sched_barrier(0);                                        \
    }

#pragma unroll 1
    for (int s = 0; s < T_LEN + 2; ++s) {
        const int ps = s & 1;
        const bool act0 = (s < T_LEN);
        const bool act1 = (s >= 1) && (s <= T_LEN);
        const bool act2 = (s >= 2);
        const int sread = act0 ? s : 0;

        const bf16* A0h = hsp(0, 1 - ps, 0); const bf16* A0l = hsp(0, 1 - ps, 1);
        const bf16* A1h = hsp(1, ps, 0);     const bf16* A1l = hsp(1, ps, 1);
        const bf16* A2h = hsp(2, 1 - ps, 0); const bf16* A2l = hsp(2, 1 - ps, 1);
        bf16* dH0h = act0 ? hsp(0, ps, 0)     : dump;
        bf16* dH0l = act0 ? hsp(0, ps, 1)     : dump;
        bf16* dH1h = act1 ? hsp(1, 1 - ps, 0) : dump;
        bf16* dH1l = act1 ? hsp(1, 1 - ps, 1) : dump;
        bf16* dH2h = act2 ? hsp(2, ps, 0)     : dump;
        bf16* dH2l = act2 ? hsp(2, ps, 1)     : dump;
        bf16* ohp  = act2 ? (outh + (size_t)(s - 2) * 65536) : dump;

        // ---- group 0: A0 x {Wh0 -> R0 (cell0), Wi1 -> R1 (cell1 partial)} ----
        ISSUE(A0h, A0l, 0, 0)
        ISSUE(A0h, A0l, 16, 1)
        WBAR(8) COMPUTE(0, 0, 1, 1, act0, act1, 0) CBAR() ISSUE(A0h, A0l, 32, 0)
        WBAR(8) COMPUTE(1, 0, 1, 1, act0, act1, 1) CBAR() ISSUE(A0h, A0l, 48, 1)
        WBAR(8) COMPUTE(0, 0, 1, 1, act0, act1, 2) CBAR() ISSUE(A1h, A1l, 0, 0)
        WBAR(8) COMPUTE(1, 0, 1, 1, act0, act1, 3)
        ATOMADD(0, a0) ATOMADD(1, a1)
        GATE(0, 0, 0, 1, sread, act0, dH0h, dH0l, nullp, creg0, bh0, 0, bh0)
        ZEROACC
        ISSUE(A1h, A1l, 16, 1)

        // ---- group 1: A1 x {Wh1 -> R0 (cell1), Wi2 -> R2 (cell2 partial)} ----
        WBAR(8) COMPUTE(0, 2, 3, 1, act1, act2, 0) CBAR() ISSUE(A1h, A1l, 32, 0)
        WBAR(8) COMPUTE(1, 2, 3, 1, act1, act2, 1) CBAR() ISSUE(A1h, A1l, 48, 1)
        WBAR(8) COMPUTE(0, 2, 3, 1, act1, act2, 2) CBAR() ISSUE(A2h, A2l, 0, 0)
        WBAR(8) COMPUTE(1, 2, 3, 1, act1, act2, 3)
        ATOMADD(0, a0) ATOMADD(2, a1)
        GATE(1, 0, 1, 0, 0, act1, dH1h, dH1l, nullp, creg1, bi1, 1, bh1)
        ZEROACC
        ISSUE(A2h, A2l, 16, 1)

        // ---- group 2: A2 x {Wh2 -> R0 (cell2)} ----
        WBAR(8) COMPUTE(0, 4, 4, 0, act2, act2, 0) CBAR() ISSUE(A2h, A2l, 32, 0)
        WBAR(8) COMPUTE(1, 4, 4, 0, act2, act2, 1) CBAR() ISSUE(A2h, A2l, 48, 1)
        WBAR(8) COMPUTE(0, 4, 4, 0, act2, act2, 2)
        WBAR(0) COMPUTE(1, 4, 4, 0, act2, act2, 3)
        ATOMADD(0, a0)
        GATE(0, 2, 1, 0, 0, act2, dH2h, dH2l, ohp, creg2, bi2, 1, bh2)
        ZEROACC

        // ---- grid barrier ----
        if (s < T_LEN + 1) {
            if (tid == 0) {
                int* slot = bar + barid * 128 + (blockIdx.x & 7) * 16;
                __hip_atomic_fetch_add(slot, 1, __ATOMIC_RELEASE,
                                       __HIP_MEMORY_SCOPE_AGENT);
                for (;;) {
                    int sum = 0;
#pragma unroll
                    for (int k = 0; k < 8; ++k)
                        sum += __hip_atomic_load(bar + barid * 128 + k * 16,
                                                 __ATOMIC_RELAXED,
                                                 __HIP_MEMORY_SCOPE_AGENT);
                    if (sum >= (int)gridDim.x) break;
                    __builtin_amdgcn_s_sleep(2);
                }
                __builtin_amdgcn_fence(__ATOMIC_ACQUIRE, "agent");
            }
            ++barid;
            __builtin_amdgcn_s_barrier();
            __builtin_amdgcn_sched_barrier(0);
        }
    }
#undef WBAR
#undef CBAR
#undef ISSUE
#undef COMPUTE
#undef ATOMADD
#undef ZEROACC
#undef GATE
}

// ---------------------------------------------------------------------------
extern "C" void kernel_launch(void* const* d_in, const int* in_sizes, int n_in,
                              void* d_out, int out_size, void* d_ws, size_t ws_size,
                              hipStream_t stream) {
    (void)in_sizes; (void)n_in; (void)out_size; (void)ws_size;
    const int*   x   = (const int*)d_in[0];
    const float* h0  = (const float*)d_in[1];
    const float* c0  = (const float*)d_in[2];
    const float* emb = (const float*)d_in[3];
    const float* W[6] = { (const float*)d_in[4],  (const float*)d_in[6],
                          (const float*)d_in[8],  (const float*)d_in[10],
                          (const float*)d_in[12], (const float*)d_in[14] };
    const float* bi0 = (const float*)d_in[5];
    const float* bh0 = (const float*)d_in[7];
    const float* bi1 = (const float*)d_in[9];
    const float* bh1 = (const float*)d_in[11];
    const float* bi2 = (const float*)d_in[13];
    const float* bh2 = (const float*)d_in[15];
    const float* Wd  = (const float*)d_in[16];
    const float* bd  = (const float*)d_in[17];

    char* ws = (char*)d_ws;
    size_t off = 0;
    float* px0 = (float*)(ws + off); off += (size_t)TBROW * GDIM * 4;
    bf16* wsp[12];
    for (int i = 0; i < 12; ++i) { wsp[i] = (bf16*)(ws + off); off += (size_t)GDIM * HDIM * 2; }
    bf16* wdb  = (bf16*)(ws + off); off += (size_t)VOCAB * HDIM * 2;
    bf16* xeh  = (bf16*)(ws + off); off += (size_t)TBROW * HDIM * 2;
    bf16* xel  = (bf16*)(ws + off); off += (size_t)TBROW * HDIM * 2;
    bf16* outh = (bf16*)(ws + off); off += (size_t)TBROW * HDIM * 2;
    bf16* hsb  = (bf16*)(ws + off); off += (size_t)12 * BATCH * HDIM * 2;
    float* cst = (float*)(ws + off); off += (size_t)3 * BATCH * HDIM * 4;
    int*  bar  = (int*)(ws + off);  off += 72 * 128 * 4;
    bf16* dump = (bf16*)(ws + off); off += (size_t)BATCH * HDIM * 2;

    // wsp[0..1]=Wi0, [2..3]=Wh0, [4..5]=Wi1, [6..7]=Wh1, [8..9]=Wi2, [10..11]=Wh2
    for (int i = 0; i < 6; ++i)
        split_kernel<<<1024, 256, 0, stream>>>(W[i], wsp[2 * i], wsp[2 * i + 1],
                                               GDIM * HDIM / 4);
    conv_kernel<<<2048, 256, 0, stream>>>(Wd, wdb, VOCAB * HDIM / 4);
    embed_kernel<<<TBROW, 256, 0, stream>>>(x, emb, xeh, xel);
    init_kernel<<<768, 256, 0, stream>>>(h0, c0, hsb, cst);
    (void)hipMemsetAsync(bar, 0, 72 * 128 * 4, stream);

    // px0 = xe @ Wi0^T + bi0 (split-3)
    dim3 gpx(GDIM / 128, TBROW / 128);
    gemm_bt<<<gpx, 256, 0, stream>>>(xeh, xel, xeh, wsp[0], wsp[0], wsp[1],
                                     3, HDIM, bi0, px0, GDIM);

    // whole recurrence: persistent weights in VGPRs (forced 256-reg budget)
    lstm_wave<<<256, 512, 0, stream>>>(
        c0,
        wsp[2], wsp[3],           // Wh0
        wsp[4], wsp[5],           // Wi1
        wsp[6], wsp[7],           // Wh1
        wsp[8], wsp[9],           // Wi2
        wsp[10], wsp[11],         // Wh2
        px0, bh0, bi1, bh1, bi2, bh2,
        hsb, outh, bar, dump);

    // decoder: d_out = outh @ Wd^T + bd
    dim3 gdec(VOCAB / 128, TBROW / 128);
    gemm_bt<<<gdec, 256, 0, stream>>>(outh, nullptr, nullptr, wdb, nullptr, nullptr,
                                      1, HDIM, bd, (float*)d_out, VOCAB);
}